// Round 9
// baseline (1024.098 us; speedup 1.0000x reference)
//
#include <hip/hip_runtime.h>

// ROI Align on MI355X.
// input: (N=8, C=256, H=100, W=100) fp32 NCHW; rois (K,5); out (K,256,7,7) fp32.
//
// Round 19: producer-consumer FUSION. Four gather restructures (r10/r13/r15/
// r18) all landed 164-167us -> the lever is the SERIALIZATION of transpose
// and gather, not either kernel's inner loop. One fused kernel, grid 1024,
// dynamic work queue: blocks claim transpose tiles (image-major) or gather
// items (batch-major) from global atomic counters; a gather item is claimed
// only when its image's per-image tile counter says complete (else the block
// transposes instead; after tiles exhaust, force-claim + bounded spin).
// Deadlock-free at ANY occupancy: blocks never wait before producing, and
// spins only target work claimed by already-dispatched blocks.
// Visibility: producer syncthreads -> threadfence (agent release) ->
// atomicAdd(ctr); consumer device-scope atomic spin -> threadfence (acquire).
// Init kernel zeroes counters + buckets ROIs by batch (map).
// Tile body = r16 transpose; item body = r18 wave-per-bin gather (verified).

typedef float nfloat4 __attribute__((ext_vector_type(4)));
typedef unsigned short nushort8 __attribute__((ext_vector_type(8)));

constexpr int   OUT_H = 7;
constexpr int   OUT_W = 7;
constexpr int   NBINS = OUT_H * OUT_W;          // 49
constexpr float SPATIAL_SCALE = 0.25f;
constexpr int   SR = 2;
constexpr int   N_DIM = 8;
constexpr int   C_DIM = 256;
constexpr int   H_DIM = 100;
constexpr int   W_DIM = 100;
constexpr int   HW    = H_DIM * W_DIM;          // 10000
constexpr size_t NHWC_BF16_BYTES = (size_t)N_DIM * HW * C_DIM * 2; // 40,960,000
constexpr int   MAX_BUCKET_K = 2048;

constexpr int   NT_SPATIAL  = (HW + 63) / 64;   // 157
constexpr int   TT_PER_IMG  = NT_SPATIAL * 4;   // 628 tiles per image
constexpr int   TT_TOTAL    = TT_PER_IMG * N_DIM; // 5024
constexpr int   TP = 65;                        // LDS stride
constexpr int   FUSED_GRID  = 1024;             // 4 blocks/CU by launch_bounds

__device__ inline unsigned short f2bf_rne(float f) {
    unsigned u = __float_as_uint(f);
    u += 0x7fffu + ((u >> 16) & 1u);    // round-to-nearest-even
    return (unsigned short)(u >> 16);
}

struct alignas(16) Geom { int lo; int hi; float wv; float mwv; };

// ---------------- init: zero meta + bucket rois by batch --------------------
// meta[0..7] = per-image transpose tile counters; meta[8]=t_ctr; meta[9]=g_ctr
__global__ __launch_bounds__(256) void init_bucket(
    const float* __restrict__ rois, int K,
    int* __restrict__ map, int* __restrict__ meta)
{
    __shared__ int cnt[8];
    __shared__ int ovfCnt, holeCnt;
    __shared__ int ovf[MAX_BUCKET_K];
    __shared__ int holes[MAX_BUCKET_K];
    int t = threadIdx.x;
    if (t < 10) meta[t] = 0;
    if (t < 8) cnt[t] = 0;
    if (t == 0) { ovfCnt = 0; holeCnt = 0; }
    for (int i = t; i < K; i += 256) map[i] = -1;
    __syncthreads();
    int per = K / 8;
    for (int i = t; i < K; i += 256) {
        int b = ((int)rois[(size_t)i * 5]) & 7;
        int r = atomicAdd(&cnt[b], 1);
        if (r < per) map[b + 8 * r] = i;
        else ovf[atomicAdd(&ovfCnt, 1)] = i;
    }
    __syncthreads();
    for (int i = t; i < K; i += 256)
        if (map[i] == -1) holes[atomicAdd(&holeCnt, 1)] = i;
    __syncthreads();
    for (int i = t; i < ovfCnt; i += 256)
        map[holes[i]] = ovf[i];
}

// ---------------- fused producer-consumer kernel ----------------------------
__global__ __launch_bounds__(256, 4) void roi_fused(
    const float* __restrict__ in, unsigned short* __restrict__ nhwc,
    const float* __restrict__ rois, const int* __restrict__ map,
    int* __restrict__ meta, float* __restrict__ out, int K)
{
    constexpr int BH = 25;                  // bins per gather item
    __shared__ union {
        float tile[64 * TP];                // 16640 B (transpose)
        float s_out[C_DIM * BH];            // 25600 B (gather)
    } sh;
    __shared__ Geom xg[OUT_W * SR];         // 14
    __shared__ Geom yg[OUT_H * SR];         // 14
    __shared__ int s_job;

    int t = threadIdx.x;
    int* ctr   = meta;                      // [0..7]
    int* t_ctr = meta + 8;
    int* g_ctr = meta + 9;
    const int GITEMS = 2 * K;
    const int PERG   = GITEMS / 8;          // items per batch-group

    for (;;) {
        if (t == 0) {
            int job = -1;
            // prefer gather when its image is ready
            int gj = atomicAdd(g_ctr, 0);   // peek
            if (gj < GITEMS) {
                int bg  = gj / PERG;
                int idx = gj - bg * PERG;
                int p   = bg + 8 * (idx >> 1);
                int k   = map[p];
                int b   = ((int)rois[(size_t)k * 5]) & 7;
                if (atomicAdd(&ctr[b], 0) >= TT_PER_IMG) {
                    int got = atomicAdd(g_ctr, 1);
                    if (got < GITEMS) job = 0x40000000 | got;
                }
            }
            if (job == -1) {
                int ti = atomicAdd(t_ctr, 1);
                if (ti < TT_TOTAL) job = ti;
                else {
                    int got = atomicAdd(g_ctr, 1);
                    job = (got < GITEMS) ? (0x40000000 | got) : -2;
                }
            }
            s_job = job;
        }
        __syncthreads();
        int job = s_job;
        if (job == -2) break;

        if (job & 0x40000000) {
            // ---------------- gather item ----------------
            int gj  = job & 0x3fffffff;
            int bg  = gj / PERG;
            int idx = gj - bg * PERG;
            int p   = bg + 8 * (idx >> 1);
            int bh  = idx & 1;
            int k   = map[p];
            int bin0 = bh * (BH - 1);
            const float* r = rois + (size_t)k * 5;
            int b = (int)r[0];

            if (t == 0) {
                while (atomicAdd(&ctr[b & 7], 0) < TT_PER_IMG)
                    __builtin_amdgcn_s_sleep(8);
                __threadfence();            // acquire: see producer's stores
            }
            __syncthreads();

            float x1 = r[1] * SPATIAL_SCALE;
            float y1 = r[2] * SPATIAL_SCALE;
            float x2 = r[3] * SPATIAL_SCALE;
            float y2 = r[4] * SPATIAL_SCALE;
            float roi_w = fmaxf(x2 - x1, 1.0f);
            float roi_h = fmaxf(y2 - y1, 1.0f);
            float bin_h = roi_h / (float)OUT_H;
            float bin_w = roi_w / (float)OUT_W;

            if (t < OUT_W * SR) {
                float g = x1 + bin_w * (((float)t + 0.5f) * 0.5f);
                float v = (g >= -1.0f && g <= (float)W_DIM) ? 1.0f : 0.0f;
                float x = fminf(fmaxf(g, 0.0f), (float)(W_DIM - 1));
                int   lo = (int)floorf(x);
                float l  = x - (float)lo;
                xg[t].lo = lo; xg[t].hi = min(lo + 1, W_DIM - 1);
                xg[t].wv = l * v; xg[t].mwv = (1.0f - l) * v;
            } else if (t >= 64 && t < 64 + OUT_H * SR) {
                int i = t - 64;
                float g = y1 + bin_h * (((float)i + 0.5f) * 0.5f);
                float v = (g >= -1.0f && g <= (float)H_DIM) ? 1.0f : 0.0f;
                float y = fminf(fmaxf(g, 0.0f), (float)(H_DIM - 1));
                int   lo = (int)floorf(y);
                float l  = y - (float)lo;
                yg[i].lo = lo; yg[i].hi = min(lo + 1, H_DIM - 1);
                yg[i].wv = l * v; yg[i].mwv = (1.0f - l) * v;
            }
            __syncthreads();

            int wave = t >> 6;
            int lane = t & 63;
            int half = lane >> 5;
            int c8   = lane & 31;
            const char* img = (const char*)nhwc
                + (size_t)b * HW * (C_DIM * 2) + c8 * 16;

            for (int bl = wave; bl < BH; bl += 4) {
                int bb = bin0 + bl;
                int oh = bb / OUT_W;
                int ow = bb - oh * OUT_W;

                Geom gys = yg[oh * SR + half];
                Geom gx0 = xg[ow * SR + 0];
                Geom gx1 = xg[ow * SR + 1];

                int   rl  = gys.lo * W_DIM, rh = gys.hi * W_DIM;
                float wyl = gys.mwv,        wyh = gys.wv;

                const uint4 v0 = *(const uint4*)(img + (size_t)(rl + gx0.lo) * (C_DIM * 2));
                const uint4 v1 = *(const uint4*)(img + (size_t)(rl + gx0.hi) * (C_DIM * 2));
                const uint4 v2 = *(const uint4*)(img + (size_t)(rh + gx0.lo) * (C_DIM * 2));
                const uint4 v3 = *(const uint4*)(img + (size_t)(rh + gx0.hi) * (C_DIM * 2));
                const uint4 v4 = *(const uint4*)(img + (size_t)(rl + gx1.lo) * (C_DIM * 2));
                const uint4 v5 = *(const uint4*)(img + (size_t)(rl + gx1.hi) * (C_DIM * 2));
                const uint4 v6 = *(const uint4*)(img + (size_t)(rh + gx1.lo) * (C_DIM * 2));
                const uint4 v7 = *(const uint4*)(img + (size_t)(rh + gx1.hi) * (C_DIM * 2));

                float w0 = wyl * gx0.mwv, w1 = wyl * gx0.wv;
                float w2 = wyh * gx0.mwv, w3 = wyh * gx0.wv;
                float w4 = wyl * gx1.mwv, w5 = wyl * gx1.wv;
                float w6 = wyh * gx1.mwv, w7 = wyh * gx1.wv;

                float acc[8] = {0.f, 0.f, 0.f, 0.f, 0.f, 0.f, 0.f, 0.f};
                auto accp = [&](float wt, const uint4& u) {
                    acc[0] = fmaf(wt, __uint_as_float(u.x << 16),         acc[0]);
                    acc[1] = fmaf(wt, __uint_as_float(u.x & 0xffff0000u), acc[1]);
                    acc[2] = fmaf(wt, __uint_as_float(u.y << 16),         acc[2]);
                    acc[3] = fmaf(wt, __uint_as_float(u.y & 0xffff0000u), acc[3]);
                    acc[4] = fmaf(wt, __uint_as_float(u.z << 16),         acc[4]);
                    acc[5] = fmaf(wt, __uint_as_float(u.z & 0xffff0000u), acc[5]);
                    acc[6] = fmaf(wt, __uint_as_float(u.w << 16),         acc[6]);
                    acc[7] = fmaf(wt, __uint_as_float(u.w & 0xffff0000u), acc[7]);
                };
                accp(w0, v0); accp(w1, v1); accp(w2, v2); accp(w3, v3);
                accp(w4, v4); accp(w5, v5); accp(w6, v6); accp(w7, v7);

                #pragma unroll
                for (int j = 0; j < 8; ++j)
                    acc[j] += __shfl_xor(acc[j], 32);

                float a0 = half ? acc[4] : acc[0];
                float a1 = half ? acc[5] : acc[1];
                float a2 = half ? acc[6] : acc[2];
                float a3 = half ? acc[7] : acc[3];
                int cb = c8 * 8 + half * 4;
                sh.s_out[(cb + 0) * BH + bl] = a0 * 0.25f;
                sh.s_out[(cb + 1) * BH + bl] = a1 * 0.25f;
                sh.s_out[(cb + 2) * BH + bl] = a2 * 0.25f;
                sh.s_out[(cb + 3) * BH + bl] = a3 * 0.25f;
            }
            __syncthreads();

            float* o = out + (size_t)k * (C_DIM * NBINS) + bin0;
            for (int i = t; i < C_DIM * BH; i += 256) {
                int c  = i / BH;
                int bl = i - c * BH;
                o[c * NBINS + bl] = sh.s_out[i];
            }
            __syncthreads();
        } else {
            // ---------------- transpose tile ----------------
            int i   = job;
            int n   = i / TT_PER_IMG;
            int rem = i - n * TT_PER_IMG;
            int c0  = (rem & 3) * 64;
            int s0  = (rem >> 2) * 64;

            int sl4 = (t & 15) * 4;
            int cq  = t >> 4;

            #pragma unroll
            for (int rr = 0; rr < 4; ++rr) {
                int cl = rr * 16 + cq;
                int s  = s0 + sl4;
                const float* src = in + ((size_t)(n * C_DIM + c0 + cl) * HW + s);
                if (s + 3 < HW) {
                    nfloat4 v = __builtin_nontemporal_load((const nfloat4*)src);
                    sh.tile[cl * TP + sl4 + 0] = v.x;
                    sh.tile[cl * TP + sl4 + 1] = v.y;
                    sh.tile[cl * TP + sl4 + 2] = v.z;
                    sh.tile[cl * TP + sl4 + 3] = v.w;
                } else {
                    #pragma unroll
                    for (int ii = 0; ii < 4; ++ii)
                        sh.tile[cl * TP + sl4 + ii] = (s + ii < HW) ? src[ii] : 0.0f;
                }
            }
            __syncthreads();

            #pragma unroll
            for (int pp = 0; pp < 2; ++pp) {
                int sp = pp * 32 + (t >> 3);
                int s  = s0 + sp;
                int c8 = (t & 7) * 8;
                if (s < HW) {
                    nushort8 h;
                    #pragma unroll
                    for (int j = 0; j < 8; ++j)
                        h[j] = f2bf_rne(sh.tile[(c8 + j) * TP + sp]);
                    *(nushort8*)(nhwc + ((size_t)n * HW + s) * C_DIM + c0 + c8) = h;
                }
            }
            __syncthreads();                // all waves' stores complete
            if (t == 0) {
                __threadfence();            // release: publish tile
                atomicAdd(&ctr[n], 1);
            }
            __syncthreads();                // protect s_job / LDS reuse
        }
    }
}

// ---------------- fallback path (two kernels, no map) -----------------------
__global__ __launch_bounds__(256) void nchw_to_nhwc_bf16(
    const float* __restrict__ in, unsigned short* __restrict__ out)
{
    __shared__ float tile[64 * TP];
    int bx = blockIdx.x;
    int t  = threadIdx.x;
    int s0 = bx * 64;
    int c0 = blockIdx.y * 64;
    int n  = blockIdx.z;

    int sl4 = (t & 15) * 4;
    int cq  = t >> 4;
    #pragma unroll
    for (int r = 0; r < 4; ++r) {
        int cl = r * 16 + cq;
        int s  = s0 + sl4;
        const float* src = in + ((size_t)(n * C_DIM + c0 + cl) * HW + s);
        if (s + 3 < HW) {
            nfloat4 v = __builtin_nontemporal_load((const nfloat4*)src);
            tile[cl * TP + sl4 + 0] = v.x;
            tile[cl * TP + sl4 + 1] = v.y;
            tile[cl * TP + sl4 + 2] = v.z;
            tile[cl * TP + sl4 + 3] = v.w;
        } else {
            #pragma unroll
            for (int i = 0; i < 4; ++i)
                tile[cl * TP + sl4 + i] = (s + i < HW) ? src[i] : 0.0f;
        }
    }
    __syncthreads();
    #pragma unroll
    for (int p = 0; p < 2; ++p) {
        int sp = p * 32 + (t >> 3);
        int s  = s0 + sp;
        int c8 = (t & 7) * 8;
        if (s < HW) {
            nushort8 h;
            #pragma unroll
            for (int j = 0; j < 8; ++j)
                h[j] = f2bf_rne(tile[(c8 + j) * TP + sp]);
            *(nushort8*)(out + ((size_t)n * HW + s) * C_DIM + c0 + c8) = h;
        }
    }
}

__global__ __launch_bounds__(256, 4) void roi_gather_bin(
    const unsigned short* __restrict__ nhwc,
    const float* __restrict__ rois,
    float* __restrict__ out, int K)
{
    constexpr int BH = 25;
    __shared__ float s_out[C_DIM * BH];
    __shared__ Geom xg[OUT_W * SR];
    __shared__ Geom yg[OUT_H * SR];

    int k    = blockIdx.x;
    int bh   = blockIdx.y;
    int bin0 = bh * (BH - 1);
    const float* r = rois + (size_t)k * 5;
    int   b  = (int)r[0];
    float x1 = r[1] * SPATIAL_SCALE;
    float y1 = r[2] * SPATIAL_SCALE;
    float x2 = r[3] * SPATIAL_SCALE;
    float y2 = r[4] * SPATIAL_SCALE;
    float roi_w = fmaxf(x2 - x1, 1.0f);
    float roi_h = fmaxf(y2 - y1, 1.0f);
    float bin_h = roi_h / (float)OUT_H;
    float bin_w = roi_w / (float)OUT_W;

    int t = threadIdx.x;
    if (t < OUT_W * SR) {
        float g = x1 + bin_w * (((float)t + 0.5f) * 0.5f);
        float v = (g >= -1.0f && g <= (float)W_DIM) ? 1.0f : 0.0f;
        float x = fminf(fmaxf(g, 0.0f), (float)(W_DIM - 1));
        int   lo = (int)floorf(x);
        float l  = x - (float)lo;
        xg[t].lo = lo; xg[t].hi = min(lo + 1, W_DIM - 1);
        xg[t].wv = l * v; xg[t].mwv = (1.0f - l) * v;
    } else if (t >= 64 && t < 64 + OUT_H * SR) {
        int i = t - 64;
        float g = y1 + bin_h * (((float)i + 0.5f) * 0.5f);
        float v = (g >= -1.0f && g <= (float)H_DIM) ? 1.0f : 0.0f;
        float y = fminf(fmaxf(g, 0.0f), (float)(H_DIM - 1));
        int   lo = (int)floorf(y);
        float l  = y - (float)lo;
        yg[i].lo = lo; yg[i].hi = min(lo + 1, H_DIM - 1);
        yg[i].wv = l * v; yg[i].mwv = (1.0f - l) * v;
    }
    __syncthreads();

    int wave = t >> 6;
    int lane = t & 63;
    int half = lane >> 5;
    int c8   = lane & 31;
    const char* img = (const char*)nhwc + (size_t)b * HW * (C_DIM * 2) + c8 * 16;

    for (int bl = wave; bl < BH; bl += 4) {
        int bb = bin0 + bl;
        int oh = bb / OUT_W;
        int ow = bb - oh * OUT_W;

        Geom gys = yg[oh * SR + half];
        Geom gx0 = xg[ow * SR + 0];
        Geom gx1 = xg[ow * SR + 1];

        int   rl  = gys.lo * W_DIM, rh = gys.hi * W_DIM;
        float wyl = gys.mwv,        wyh = gys.wv;

        const uint4 v0 = *(const uint4*)(img + (size_t)(rl + gx0.lo) * (C_DIM * 2));
        const uint4 v1 = *(const uint4*)(img + (size_t)(rl + gx0.hi) * (C_DIM * 2));
        const uint4 v2 = *(const uint4*)(img + (size_t)(rh + gx0.lo) * (C_DIM * 2));
        const uint4 v3 = *(const uint4*)(img + (size_t)(rh + gx0.hi) * (C_DIM * 2));
        const uint4 v4 = *(const uint4*)(img + (size_t)(rl + gx1.lo) * (C_DIM * 2));
        const uint4 v5 = *(const uint4*)(img + (size_t)(rl + gx1.hi) * (C_DIM * 2));
        const uint4 v6 = *(const uint4*)(img + (size_t)(rh + gx1.lo) * (C_DIM * 2));
        const uint4 v7 = *(const uint4*)(img + (size_t)(rh + gx1.hi) * (C_DIM * 2));

        float w0 = wyl * gx0.mwv, w1 = wyl * gx0.wv;
        float w2 = wyh * gx0.mwv, w3 = wyh * gx0.wv;
        float w4 = wyl * gx1.mwv, w5 = wyl * gx1.wv;
        float w6 = wyh * gx1.mwv, w7 = wyh * gx1.wv;

        float acc[8] = {0.f, 0.f, 0.f, 0.f, 0.f, 0.f, 0.f, 0.f};
        auto accp = [&](float wt, const uint4& u) {
            acc[0] = fmaf(wt, __uint_as_float(u.x << 16),         acc[0]);
            acc[1] = fmaf(wt, __uint_as_float(u.x & 0xffff0000u), acc[1]);
            acc[2] = fmaf(wt, __uint_as_float(u.y << 16),         acc[2]);
            acc[3] = fmaf(wt, __uint_as_float(u.y & 0xffff0000u), acc[3]);
            acc[4] = fmaf(wt, __uint_as_float(u.z << 16),         acc[4]);
            acc[5] = fmaf(wt, __uint_as_float(u.z & 0xffff0000u), acc[5]);
            acc[6] = fmaf(wt, __uint_as_float(u.w << 16),         acc[6]);
            acc[7] = fmaf(wt, __uint_as_float(u.w & 0xffff0000u), acc[7]);
        };
        accp(w0, v0); accp(w1, v1); accp(w2, v2); accp(w3, v3);
        accp(w4, v4); accp(w5, v5); accp(w6, v6); accp(w7, v7);

        #pragma unroll
        for (int j = 0; j < 8; ++j)
            acc[j] += __shfl_xor(acc[j], 32);

        float a0 = half ? acc[4] : acc[0];
        float a1 = half ? acc[5] : acc[1];
        float a2 = half ? acc[6] : acc[2];
        float a3 = half ? acc[7] : acc[3];
        int cb = c8 * 8 + half * 4;
        s_out[(cb + 0) * BH + bl] = a0 * 0.25f;
        s_out[(cb + 1) * BH + bl] = a1 * 0.25f;
        s_out[(cb + 2) * BH + bl] = a2 * 0.25f;
        s_out[(cb + 3) * BH + bl] = a3 * 0.25f;
    }
    __syncthreads();

    float* o = out + (size_t)k * (C_DIM * NBINS) + bin0;
    for (int i = t; i < C_DIM * BH; i += 256) {
        int c  = i / BH;
        int bl = i - c * BH;
        o[c * NBINS + bl] = s_out[i];
    }
}

// ---------------- fallback (round-0 baseline) if ws too small ---------------
__global__ __launch_bounds__(256) void roi_align_naive(
    const float* __restrict__ input, const float* __restrict__ rois,
    float* __restrict__ out, int K)
{
    int idx = blockIdx.x * blockDim.x + threadIdx.x;
    int total = K * C_DIM * OUT_H * OUT_W;
    if (idx >= total) return;
    int ow = idx % OUT_W;
    int oh = (idx / OUT_W) % OUT_H;
    int c  = (idx / (OUT_W * OUT_H)) % C_DIM;
    int k  = idx / (OUT_W * OUT_H * C_DIM);
    const float* r = rois + (size_t)k * 5;
    int   b  = (int)r[0];
    float x1 = r[1] * SPATIAL_SCALE, y1 = r[2] * SPATIAL_SCALE;
    float x2 = r[3] * SPATIAL_SCALE, y2 = r[4] * SPATIAL_SCALE;
    float roi_w = fmaxf(x2 - x1, 1.0f), roi_h = fmaxf(y2 - y1, 1.0f);
    float bin_h = roi_h / OUT_H, bin_w = roi_w / OUT_W;
    const float* inp = input + ((size_t)b * C_DIM + c) * HW;
    float acc = 0.0f;
    #pragma unroll
    for (int sy = 0; sy < SR; ++sy) {
        float gy = y1 + bin_h * (((float)(oh * SR + sy) + 0.5f) / SR);
        bool vy = (gy >= -1.0f) && (gy <= (float)H_DIM);
        float y = fminf(fmaxf(gy, 0.0f), (float)(H_DIM - 1));
        int yl = (int)floorf(y); float ly = y - yl; int yh = min(yl + 1, H_DIM - 1);
        #pragma unroll
        for (int sx = 0; sx < SR; ++sx) {
            float gx = x1 + bin_w * (((float)(ow * SR + sx) + 0.5f) / SR);
            bool vx = (gx >= -1.0f) && (gx <= (float)W_DIM);
            float x = fminf(fmaxf(gx, 0.0f), (float)(W_DIM - 1));
            int xl = (int)floorf(x); float lx = x - xl; int xh = min(xl + 1, W_DIM - 1);
            float v = (1.0f - ly) * ((1.0f - lx) * inp[yl * W_DIM + xl] + lx * inp[yl * W_DIM + xh])
                    + ly * ((1.0f - lx) * inp[yh * W_DIM + xl] + lx * inp[yh * W_DIM + xh]);
            if (vy && vx) acc += v;
        }
    }
    out[idx] = acc * 0.25f;
}

extern "C" void kernel_launch(void* const* d_in, const int* in_sizes, int n_in,
                              void* d_out, int out_size, void* d_ws, size_t ws_size,
                              hipStream_t stream) {
    const float* input = (const float*)d_in[0];
    const float* rois  = (const float*)d_in[1];
    float* out = (float*)d_out;
    int K = in_sizes[1] / 5;

    size_t need_fused = NHWC_BF16_BYTES + (size_t)K * sizeof(int) + 16 * sizeof(int);
    if (ws_size >= need_fused && K <= MAX_BUCKET_K && (K % 8) == 0) {
        unsigned short* nhwc = (unsigned short*)d_ws;
        int* map  = (int*)((char*)d_ws + NHWC_BF16_BYTES);
        int* meta = map + K;
        init_bucket<<<1, 256, 0, stream>>>(rois, K, map, meta);
        roi_fused<<<FUSED_GRID, 256, 0, stream>>>(input, nhwc, rois, map, meta, out, K);
    } else if (ws_size >= NHWC_BF16_BYTES) {
        unsigned short* nhwc = (unsigned short*)d_ws;
        dim3 tgrid(NT_SPATIAL, C_DIM / 64, N_DIM);
        nchw_to_nhwc_bf16<<<tgrid, 256, 0, stream>>>(input, nhwc);
        dim3 ggrid(K, 2);
        roi_gather_bin<<<ggrid, 256, 0, stream>>>(nhwc, rois, out, K);
    } else {
        int total = K * C_DIM * OUT_H * OUT_W;
        roi_align_naive<<<(total + 255) / 256, 256, 0, stream>>>(input, rois, out, K);
    }
}

// Round 10
// 236.636 us; speedup vs baseline: 4.3277x; 4.3277x over previous
//
#include <hip/hip_runtime.h>

// ROI Align on MI355X.
// input: (N=8, C=256, H=100, W=100) fp32 NCHW; rois (K,5); out (K,256,7,7) fp32.
//
// Round 20: revert to two-kernel (r19 fusion = scheduling disaster: claim-
// before-verify let blocks capture not-yet-ready gather items and spin
// instead of producing; VALU 2.4%). Budget now settled (fill once/rep):
// floor ~75us, T ~45, G ~40. Attack both kernels' latency-boundness:
//  - transpose: 64ch x 128sp tiles (8 NT loads/thread, 512B read segments,
//    2528 blocks) -> deeper MLP, better HBM sequentiality.
//  - gather: r18 wave-per-bin body, s_out staging REMOVED (direct 4B global
//    stores; L2 coalesces). LDS 25.6KB -> 0.3KB, occupancy 6 -> 8 blocks/CU,
//    no copy-out barrier.

typedef float nfloat4 __attribute__((ext_vector_type(4)));
typedef unsigned short nushort8 __attribute__((ext_vector_type(8)));

constexpr int   OUT_H = 7;
constexpr int   OUT_W = 7;
constexpr int   NBINS = OUT_H * OUT_W;          // 49
constexpr float SPATIAL_SCALE = 0.25f;
constexpr int   SR = 2;
constexpr int   N_DIM = 8;
constexpr int   C_DIM = 256;
constexpr int   H_DIM = 100;
constexpr int   W_DIM = 100;
constexpr int   HW    = H_DIM * W_DIM;          // 10000
constexpr size_t NHWC_BF16_BYTES = (size_t)N_DIM * HW * C_DIM * 2; // 40,960,000
constexpr int   MAX_BUCKET_K = 2048;

constexpr int   SP_TILE = 128;
constexpr int   NT_SP   = (HW + SP_TILE - 1) / SP_TILE;   // 79
constexpr int   TP2     = 129;                  // LDS stride (floats)

__device__ inline unsigned short f2bf_rne(float f) {
    unsigned u = __float_as_uint(f);
    u += 0x7fffu + ((u >> 16) & 1u);    // round-to-nearest-even
    return (unsigned short)(u >> 16);
}

// ---------------- transpose+cast + bucket (fused) ---------------------------
// blocks x<79: NCHW fp32 -> NHWC bf16, 64ch x 128sp tile, LDS stride 129.
// block (79,0,0): bucket -> map[k] = ROI index with batch ~= k%8.
union TransposeSh {
    float tile[64 * TP2];                                  // 33024 B
    struct {
        int cnt[8]; int ovfCnt; int holeCnt;
        int ovf[MAX_BUCKET_K]; int holes[MAX_BUCKET_K];    // 16424 B
    } bk;
};

__global__ __launch_bounds__(256) void nchw_to_nhwc_bf16(
    const float* __restrict__ in, unsigned short* __restrict__ out,
    const float* __restrict__ rois, int K, int* __restrict__ map)
{
    __shared__ TransposeSh sh;
    int bx = blockIdx.x;
    int t  = threadIdx.x;

    if (bx == NT_SP) {
        // ---- bucket branch: one block does the batch->position map ----
        if (blockIdx.y != 0 || blockIdx.z != 0 || map == nullptr) return;
        if (t < 8) sh.bk.cnt[t] = 0;
        if (t == 0) { sh.bk.ovfCnt = 0; sh.bk.holeCnt = 0; }
        for (int i = t; i < K; i += 256) map[i] = -1;
        __syncthreads();
        int per = K / 8;
        for (int i = t; i < K; i += 256) {
            int b = ((int)rois[(size_t)i * 5]) & 7;
            int r = atomicAdd(&sh.bk.cnt[b], 1);
            if (r < per) map[b + 8 * r] = i;
            else sh.bk.ovf[atomicAdd(&sh.bk.ovfCnt, 1)] = i;
        }
        __syncthreads();
        for (int i = t; i < K; i += 256)
            if (map[i] == -1) sh.bk.holes[atomicAdd(&sh.bk.holeCnt, 1)] = i;
        __syncthreads();
        for (int i = t; i < sh.bk.ovfCnt; i += 256)
            map[sh.bk.holes[i]] = sh.bk.ovf[i];
        return;
    }

    // ---- transpose branch ----
    int s0 = bx * SP_TILE;
    int c0 = blockIdx.y * 64;
    int n  = blockIdx.z;
    bool full = (s0 + SP_TILE <= HW);

    int sl4 = (t & 31) * 4;            // 0..124
    int cw  = t >> 5;                  // 0..7

    #pragma unroll
    for (int r = 0; r < 8; ++r) {
        int cl = r * 8 + cw;
        int s  = s0 + sl4;
        const float* src = in + ((size_t)(n * C_DIM + c0 + cl) * HW + s);
        if (full) {
            nfloat4 v = __builtin_nontemporal_load((const nfloat4*)src);
            sh.tile[cl * TP2 + sl4 + 0] = v.x;
            sh.tile[cl * TP2 + sl4 + 1] = v.y;
            sh.tile[cl * TP2 + sl4 + 2] = v.z;
            sh.tile[cl * TP2 + sl4 + 3] = v.w;
        } else {
            #pragma unroll
            for (int i = 0; i < 4; ++i)
                sh.tile[cl * TP2 + sl4 + i] = (s + i < HW) ? src[i] : 0.0f;
        }
    }
    __syncthreads();

    // write-out: 4 passes, 8 channels/thread, one 16B ushort8 store each.
    // LDS read bank = ((c8+j)*129 + sp) % 32 = (8*(t&7)+j+(t>>3)) % 32 -> 2-way.
    #pragma unroll
    for (int p = 0; p < 4; ++p) {
        int sp = p * 32 + (t >> 3);
        int s  = s0 + sp;
        int c8 = (t & 7) * 8;
        if (s < HW) {
            nushort8 h;
            #pragma unroll
            for (int j = 0; j < 8; ++j)
                h[j] = f2bf_rne(sh.tile[(c8 + j) * TP2 + sp]);
            *(nushort8*)(out + ((size_t)n * HW + s) * C_DIM + c0 + c8) = h;
        }
    }
}

// ---------------- gather: wave-per-bin, direct global writes ----------------
// block = (ROI via map, bin-half); wave = one bin per iteration (bl stride 4).
// lane = half*32 + c8: half = sy (and which 8 of 16 (sample,corner) pairs),
// c8 = channel octet. Per bin: 3 broadcast ds_read_b128 (wave-uniform geom),
// 8 uint4 loads (each 2x512B contiguous segments), 64 fma, 8 shfl_xor(32),
// then 4 DIRECT 4B global stores per lane (no LDS staging -> occupancy 8
// blocks/CU, no copy-out barrier; L2 coalesces the scattered lines).
// Weights validity-premultiplied; bin 24 written twice (bit-identical).
struct alignas(16) Geom { int lo; int hi; float wv; float mwv; };

__global__ __launch_bounds__(256, 8) void roi_gather_bin(
    const unsigned short* __restrict__ nhwc,
    const float* __restrict__ rois,
    const int* __restrict__ map,
    float* __restrict__ out, int K)
{
    constexpr int BH = 25;                 // bins per block
    __shared__ Geom xg[OUT_W * SR];        // 14
    __shared__ Geom yg[OUT_H * SR];        // 14

    int k    = map ? map[blockIdx.x] : (int)blockIdx.x;
    int bh   = blockIdx.y;                 // 0 -> bins 0..24, 1 -> bins 24..48
    int bin0 = bh * (BH - 1);
    const float* r = rois + (size_t)k * 5;
    int   b  = (int)r[0];
    float x1 = r[1] * SPATIAL_SCALE;
    float y1 = r[2] * SPATIAL_SCALE;
    float x2 = r[3] * SPATIAL_SCALE;
    float y2 = r[4] * SPATIAL_SCALE;
    float roi_w = fmaxf(x2 - x1, 1.0f);
    float roi_h = fmaxf(y2 - y1, 1.0f);
    float bin_h = roi_h / (float)OUT_H;
    float bin_w = roi_w / (float)OUT_W;

    int t = threadIdx.x;
    // fill geometry: threads 0..13 -> x, 64..77 -> y (separate waves)
    if (t < OUT_W * SR) {
        float g = x1 + bin_w * (((float)t + 0.5f) * 0.5f);
        float v = (g >= -1.0f && g <= (float)W_DIM) ? 1.0f : 0.0f;
        float x = fminf(fmaxf(g, 0.0f), (float)(W_DIM - 1));
        int   lo = (int)floorf(x);
        float l  = x - (float)lo;
        xg[t].lo = lo; xg[t].hi = min(lo + 1, W_DIM - 1);
        xg[t].wv = l * v; xg[t].mwv = (1.0f - l) * v;
    } else if (t >= 64 && t < 64 + OUT_H * SR) {
        int i = t - 64;
        float g = y1 + bin_h * (((float)i + 0.5f) * 0.5f);
        float v = (g >= -1.0f && g <= (float)H_DIM) ? 1.0f : 0.0f;
        float y = fminf(fmaxf(g, 0.0f), (float)(H_DIM - 1));
        int   lo = (int)floorf(y);
        float l  = y - (float)lo;
        yg[i].lo = lo; yg[i].hi = min(lo + 1, H_DIM - 1);
        yg[i].wv = l * v; yg[i].mwv = (1.0f - l) * v;
    }
    __syncthreads();

    int wave = t >> 6;
    int lane = t & 63;
    int half = lane >> 5;                  // sample row sy; pair-set selector
    int c8   = lane & 31;                  // channel octet 0..31

    const char* img = (const char*)nhwc + (size_t)b * HW * (C_DIM * 2) + c8 * 16;
    float* o = out + (size_t)k * (C_DIM * NBINS);
    int cb = c8 * 8 + half * 4;

    for (int bl = wave; bl < BH; bl += 4) {
        int bb = bin0 + bl;
        int oh = bb / OUT_W;               // wave-uniform
        int ow = bb - oh * OUT_W;

        Geom gys = yg[oh * SR + half];     // this half's sample row
        Geom gx0 = xg[ow * SR + 0];
        Geom gx1 = xg[ow * SR + 1];

        int   rl  = gys.lo * W_DIM, rh = gys.hi * W_DIM;
        float wyl = gys.mwv,        wyh = gys.wv;

        // 8 (sample-x, corner) pairs for this half's row; 2x512B segments each
        const uint4 v0 = *(const uint4*)(img + (size_t)(rl + gx0.lo) * (C_DIM * 2));
        const uint4 v1 = *(const uint4*)(img + (size_t)(rl + gx0.hi) * (C_DIM * 2));
        const uint4 v2 = *(const uint4*)(img + (size_t)(rh + gx0.lo) * (C_DIM * 2));
        const uint4 v3 = *(const uint4*)(img + (size_t)(rh + gx0.hi) * (C_DIM * 2));
        const uint4 v4 = *(const uint4*)(img + (size_t)(rl + gx1.lo) * (C_DIM * 2));
        const uint4 v5 = *(const uint4*)(img + (size_t)(rl + gx1.hi) * (C_DIM * 2));
        const uint4 v6 = *(const uint4*)(img + (size_t)(rh + gx1.lo) * (C_DIM * 2));
        const uint4 v7 = *(const uint4*)(img + (size_t)(rh + gx1.hi) * (C_DIM * 2));

        float w0 = wyl * gx0.mwv, w1 = wyl * gx0.wv;
        float w2 = wyh * gx0.mwv, w3 = wyh * gx0.wv;
        float w4 = wyl * gx1.mwv, w5 = wyl * gx1.wv;
        float w6 = wyh * gx1.mwv, w7 = wyh * gx1.wv;

        float acc[8] = {0.f, 0.f, 0.f, 0.f, 0.f, 0.f, 0.f, 0.f};
        auto accp = [&](float wt, const uint4& u) {
            acc[0] = fmaf(wt, __uint_as_float(u.x << 16),         acc[0]);
            acc[1] = fmaf(wt, __uint_as_float(u.x & 0xffff0000u), acc[1]);
            acc[2] = fmaf(wt, __uint_as_float(u.y << 16),         acc[2]);
            acc[3] = fmaf(wt, __uint_as_float(u.y & 0xffff0000u), acc[3]);
            acc[4] = fmaf(wt, __uint_as_float(u.z << 16),         acc[4]);
            acc[5] = fmaf(wt, __uint_as_float(u.z & 0xffff0000u), acc[5]);
            acc[6] = fmaf(wt, __uint_as_float(u.w << 16),         acc[6]);
            acc[7] = fmaf(wt, __uint_as_float(u.w & 0xffff0000u), acc[7]);
        };
        accp(w0, v0); accp(w1, v1); accp(w2, v2); accp(w3, v3);
        accp(w4, v4); accp(w5, v5); accp(w6, v6); accp(w7, v7);

        // combine the two halves (sy=0 pairs + sy=1 pairs)
        #pragma unroll
        for (int j = 0; j < 8; ++j)
            acc[j] += __shfl_xor(acc[j], 32);

        // each half stores 4 of the 8 channels (static acc indices), directly
        float a0 = half ? acc[4] : acc[0];
        float a1 = half ? acc[5] : acc[1];
        float a2 = half ? acc[6] : acc[2];
        float a3 = half ? acc[7] : acc[3];
        o[(cb + 0) * NBINS + bb] = a0 * 0.25f;
        o[(cb + 1) * NBINS + bb] = a1 * 0.25f;
        o[(cb + 2) * NBINS + bb] = a2 * 0.25f;
        o[(cb + 3) * NBINS + bb] = a3 * 0.25f;
    }
}

// ---------------- fallback (round-0 baseline) if ws too small ---------------
__global__ __launch_bounds__(256) void roi_align_naive(
    const float* __restrict__ input, const float* __restrict__ rois,
    float* __restrict__ out, int K)
{
    int idx = blockIdx.x * blockDim.x + threadIdx.x;
    int total = K * C_DIM * OUT_H * OUT_W;
    if (idx >= total) return;
    int ow = idx % OUT_W;
    int oh = (idx / OUT_W) % OUT_H;
    int c  = (idx / (OUT_W * OUT_H)) % C_DIM;
    int k  = idx / (OUT_W * OUT_H * C_DIM);
    const float* r = rois + (size_t)k * 5;
    int   b  = (int)r[0];
    float x1 = r[1] * SPATIAL_SCALE, y1 = r[2] * SPATIAL_SCALE;
    float x2 = r[3] * SPATIAL_SCALE, y2 = r[4] * SPATIAL_SCALE;
    float roi_w = fmaxf(x2 - x1, 1.0f), roi_h = fmaxf(y2 - y1, 1.0f);
    float bin_h = roi_h / OUT_H, bin_w = roi_w / OUT_W;
    const float* inp = input + ((size_t)b * C_DIM + c) * HW;
    float acc = 0.0f;
    #pragma unroll
    for (int sy = 0; sy < SR; ++sy) {
        float gy = y1 + bin_h * (((float)(oh * SR + sy) + 0.5f) / SR);
        bool vy = (gy >= -1.0f) && (gy <= (float)H_DIM);
        float y = fminf(fmaxf(gy, 0.0f), (float)(H_DIM - 1));
        int yl = (int)floorf(y); float ly = y - yl; int yh = min(yl + 1, H_DIM - 1);
        #pragma unroll
        for (int sx = 0; sx < SR; ++sx) {
            float gx = x1 + bin_w * (((float)(ow * SR + sx) + 0.5f) / SR);
            bool vx = (gx >= -1.0f) && (gx <= (float)W_DIM);
            float x = fminf(fmaxf(gx, 0.0f), (float)(W_DIM - 1));
            int xl = (int)floorf(x); float lx = x - xl; int xh = min(xl + 1, W_DIM - 1);
            float v = (1.0f - ly) * ((1.0f - lx) * inp[yl * W_DIM + xl] + lx * inp[yl * W_DIM + xh])
                    + ly * ((1.0f - lx) * inp[yh * W_DIM + xl] + lx * inp[yh * W_DIM + xh]);
            if (vy && vx) acc += v;
        }
    }
    out[idx] = acc * 0.25f;
}

extern "C" void kernel_launch(void* const* d_in, const int* in_sizes, int n_in,
                              void* d_out, int out_size, void* d_ws, size_t ws_size,
                              hipStream_t stream) {
    const float* input = (const float*)d_in[0];
    const float* rois  = (const float*)d_in[1];
    float* out = (float*)d_out;
    int K = in_sizes[1] / 5;

    if (ws_size >= NHWC_BF16_BYTES + (size_t)K * sizeof(int) && K <= MAX_BUCKET_K) {
        unsigned short* nhwc = (unsigned short*)d_ws;
        int* map = (int*)((char*)d_ws + NHWC_BF16_BYTES);
        dim3 tgrid(NT_SP + 1, C_DIM / 64, N_DIM);    // 80 x 4 x 8 (+1 = bucket)
        nchw_to_nhwc_bf16<<<tgrid, 256, 0, stream>>>(input, nhwc, rois, K, map);
        dim3 ggrid(K, 2);
        roi_gather_bin<<<ggrid, 256, 0, stream>>>(nhwc, rois, map, out, K);
    } else if (ws_size >= NHWC_BF16_BYTES) {
        unsigned short* nhwc = (unsigned short*)d_ws;
        dim3 tgrid(NT_SP, C_DIM / 64, N_DIM);
        nchw_to_nhwc_bf16<<<tgrid, 256, 0, stream>>>(input, nhwc, rois, K, nullptr);
        dim3 ggrid(K, 2);
        roi_gather_bin<<<ggrid, 256, 0, stream>>>(nhwc, rois, nullptr, out, K);
    } else {
        int total = K * C_DIM * OUT_H * OUT_W;
        roi_align_naive<<<(total + 255) / 256, 256, 0, stream>>>(input, rois, out, K);
    }
}

// Round 11
// 172.171 us; speedup vs baseline: 5.9482x; 1.3744x over previous
//
#include <hip/hip_runtime.h>

// ROI Align on MI355X.
// input: (N=8, C=256, H=100, W=100) fp32 NCHW; rois (K,5); out (K,256,7,7) fp32.
//
// Round 21: gather reverted to r16's quarter-channel STAGED version (r20's
// direct 4B stores caused 4.5x write amplification: 223MB WRITE for a 50MB
// output, partial-line writes evicted between waves; staging exists to make
// stores line-complete). Transpose keeps r20's 128-sp tiles as the single
// live delta (512B read segments, 8 NT loads/thread) - it was never
// implicated in r20's regression and transpose is the largest remaining
// controllable slice (est ~49us vs 20us traffic floor).

typedef float nfloat4 __attribute__((ext_vector_type(4)));
typedef unsigned short nushort8 __attribute__((ext_vector_type(8)));

constexpr int   OUT_H = 7;
constexpr int   OUT_W = 7;
constexpr int   NBINS = OUT_H * OUT_W;          // 49
constexpr int   NPAIRS = (NBINS + 1) / 2;       // 25 (last pair has 1 bin)
constexpr float SPATIAL_SCALE = 0.25f;
constexpr int   SR = 2;
constexpr int   N_DIM = 8;
constexpr int   C_DIM = 256;
constexpr int   H_DIM = 100;
constexpr int   W_DIM = 100;
constexpr int   HW    = H_DIM * W_DIM;          // 10000
constexpr size_t NHWC_BF16_BYTES = (size_t)N_DIM * HW * C_DIM * 2; // 40,960,000
constexpr int   MAX_BUCKET_K = 2048;

constexpr int   SP_TILE = 128;
constexpr int   NT_SP   = (HW + SP_TILE - 1) / SP_TILE;   // 79
constexpr int   TP2     = 129;                  // LDS stride (floats)

__device__ inline unsigned short f2bf_rne(float f) {
    unsigned u = __float_as_uint(f);
    u += 0x7fffu + ((u >> 16) & 1u);    // round-to-nearest-even
    return (unsigned short)(u >> 16);
}

// ---------------- transpose+cast + bucket (fused) ---------------------------
// blocks x<79: NCHW fp32 -> NHWC bf16, 64ch x 128sp tile, LDS stride 129.
// block (79,0,0): bucket -> map[k] = ROI index with batch ~= k%8.
union TransposeSh {
    float tile[64 * TP2];                                  // 33024 B
    struct {
        int cnt[8]; int ovfCnt; int holeCnt;
        int ovf[MAX_BUCKET_K]; int holes[MAX_BUCKET_K];    // 16424 B
    } bk;
};

__global__ __launch_bounds__(256) void nchw_to_nhwc_bf16(
    const float* __restrict__ in, unsigned short* __restrict__ out,
    const float* __restrict__ rois, int K, int* __restrict__ map)
{
    __shared__ TransposeSh sh;
    int bx = blockIdx.x;
    int t  = threadIdx.x;

    if (bx == NT_SP) {
        // ---- bucket branch: one block does the batch->position map ----
        if (blockIdx.y != 0 || blockIdx.z != 0 || map == nullptr) return;
        if (t < 8) sh.bk.cnt[t] = 0;
        if (t == 0) { sh.bk.ovfCnt = 0; sh.bk.holeCnt = 0; }
        for (int i = t; i < K; i += 256) map[i] = -1;
        __syncthreads();
        int per = K / 8;
        for (int i = t; i < K; i += 256) {
            int b = ((int)rois[(size_t)i * 5]) & 7;
            int r = atomicAdd(&sh.bk.cnt[b], 1);
            if (r < per) map[b + 8 * r] = i;
            else sh.bk.ovf[atomicAdd(&sh.bk.ovfCnt, 1)] = i;
        }
        __syncthreads();
        for (int i = t; i < K; i += 256)
            if (map[i] == -1) sh.bk.holes[atomicAdd(&sh.bk.holeCnt, 1)] = i;
        __syncthreads();
        for (int i = t; i < sh.bk.ovfCnt; i += 256)
            map[sh.bk.holes[i]] = sh.bk.ovf[i];
        return;
    }

    // ---- transpose branch ----
    int s0 = bx * SP_TILE;
    int c0 = blockIdx.y * 64;
    int n  = blockIdx.z;
    bool full = (s0 + SP_TILE <= HW);

    int sl4 = (t & 31) * 4;            // 0..124
    int cw  = t >> 5;                  // 0..7

    #pragma unroll
    for (int r = 0; r < 8; ++r) {
        int cl = r * 8 + cw;
        int s  = s0 + sl4;
        const float* src = in + ((size_t)(n * C_DIM + c0 + cl) * HW + s);
        if (full) {
            nfloat4 v = __builtin_nontemporal_load((const nfloat4*)src);
            sh.tile[cl * TP2 + sl4 + 0] = v.x;
            sh.tile[cl * TP2 + sl4 + 1] = v.y;
            sh.tile[cl * TP2 + sl4 + 2] = v.z;
            sh.tile[cl * TP2 + sl4 + 3] = v.w;
        } else {
            #pragma unroll
            for (int i = 0; i < 4; ++i)
                sh.tile[cl * TP2 + sl4 + i] = (s + i < HW) ? src[i] : 0.0f;
        }
    }
    __syncthreads();

    // write-out: 4 passes, 8 channels/thread, one 16B ushort8 store each.
    // LDS read bank = ((c8+j)*129 + sp) % 32 = (8*(t&7)+j+(t>>3)) % 32 -> 2-way.
    #pragma unroll
    for (int p = 0; p < 4; ++p) {
        int sp = p * 32 + (t >> 3);
        int s  = s0 + sp;
        int c8 = (t & 7) * 8;
        if (s < HW) {
            nushort8 h;
            #pragma unroll
            for (int j = 0; j < 8; ++j)
                h[j] = f2bf_rne(sh.tile[(c8 + j) * TP2 + sp]);
            *(nushort8*)(out + ((size_t)n * HW + s) * C_DIM + c0 + c8) = h;
        }
    }
}

// ---------------- gather: quarter-channel blocks, 2-bin pairs per wave ------
// block = (ROI via map, 64-ch quarter); wave iterates bin-PAIRS (stride 4).
// lane = hi*32 + q*8 + cg:  hi = which bin of the pair, q = corner, cg = 8-ch
// group. Per iteration: 8 broadcast Geom reads + 8 independent uint4 loads
// (4 samples x this lane's corner, both bins) + 32 fma; corner reduce =
// shfl_xor(8),shfl_xor(16) within each 32-lane half (2 bins per 16 shfl).
// s_out STAGING kept: assembles line-complete contiguous stores (r20 showed
// direct scattered 4B stores cost 4.5x write amplification).
struct alignas(16) Geom { int lo; int hi; float wv; float mwv; };

__global__ __launch_bounds__(256, 6) void roi_gather_q(
    const unsigned short* __restrict__ nhwc,
    const float* __restrict__ rois,
    const int* __restrict__ map,
    float* __restrict__ out, int K)
{
    __shared__ float s_out[64 * NBINS];    // 12544 B
    __shared__ Geom xg[OUT_W * SR];        // 14
    __shared__ Geom yg[OUT_H * SR];        // 14

    int k  = map ? map[blockIdx.x] : (int)blockIdx.x;
    int qa = blockIdx.y;                   // channel quarter 0..3
    const float* r = rois + (size_t)k * 5;
    int   b  = (int)r[0];
    float x1 = r[1] * SPATIAL_SCALE;
    float y1 = r[2] * SPATIAL_SCALE;
    float x2 = r[3] * SPATIAL_SCALE;
    float y2 = r[4] * SPATIAL_SCALE;
    float roi_w = fmaxf(x2 - x1, 1.0f);
    float roi_h = fmaxf(y2 - y1, 1.0f);
    float bin_h = roi_h / (float)OUT_H;
    float bin_w = roi_w / (float)OUT_W;

    int t = threadIdx.x;
    // fill geometry: threads 0..13 -> x, 64..77 -> y (separate waves)
    if (t < OUT_W * SR) {
        float g = x1 + bin_w * (((float)t + 0.5f) * 0.5f);
        float v = (g >= -1.0f && g <= (float)W_DIM) ? 1.0f : 0.0f;
        float x = fminf(fmaxf(g, 0.0f), (float)(W_DIM - 1));
        int   lo = (int)floorf(x);
        float l  = x - (float)lo;
        xg[t].lo = lo; xg[t].hi = min(lo + 1, W_DIM - 1);
        xg[t].wv = l * v; xg[t].mwv = (1.0f - l) * v;
    } else if (t >= 64 && t < 64 + OUT_H * SR) {
        int i = t - 64;
        float g = y1 + bin_h * (((float)i + 0.5f) * 0.5f);
        float v = (g >= -1.0f && g <= (float)H_DIM) ? 1.0f : 0.0f;
        float y = fminf(fmaxf(g, 0.0f), (float)(H_DIM - 1));
        int   lo = (int)floorf(y);
        float l  = y - (float)lo;
        yg[i].lo = lo; yg[i].hi = min(lo + 1, H_DIM - 1);
        yg[i].wv = l * v; yg[i].mwv = (1.0f - l) * v;
    }
    __syncthreads();

    int wave = t >> 6;
    int lane = t & 63;
    int hi   = lane >> 5;                  // which bin of the pair
    int q    = (lane >> 3) & 3;            // corner: 0=ll 1=lh 2=hl 3=hh
    int cg   = lane & 7;                   // 8-channel group within quarter
    int qy   = q >> 1;
    int qx   = q & 1;

    const char* img = (const char*)nhwc
        + (size_t)b * HW * (C_DIM * 2) + qa * 128 + cg * 16;

    for (int p = wave; p < NPAIRS; p += 4) {
        int bb  = 2 * p + hi;                      // 0..49 (49 = pad)
        int bbc = bb < NBINS ? bb : NBINS - 1;
        int oh  = bbc / OUT_W;
        int ow  = bbc - oh * OUT_W;

        Geom gy0 = yg[oh * SR + 0];
        Geom gy1 = yg[oh * SR + 1];
        Geom gx0 = xg[ow * SR + 0];
        Geom gx1 = xg[ow * SR + 1];
        int   yy0 = qy ? gy0.hi : gy0.lo;  float wy0 = qy ? gy0.wv : gy0.mwv;
        int   yy1 = qy ? gy1.hi : gy1.lo;  float wy1 = qy ? gy1.wv : gy1.mwv;
        int   xx0 = qx ? gx0.hi : gx0.lo;  float wx0 = qx ? gx0.wv : gx0.mwv;
        int   xx1 = qx ? gx1.hi : gx1.lo;  float wx1 = qx ? gx1.wv : gx1.mwv;

        // 4 samples (sy,sx) for this lane's corner, this lane's bin
        uint4 v0 = *(const uint4*)(img + (size_t)(yy0 * W_DIM + xx0) * (C_DIM * 2));
        uint4 v1 = *(const uint4*)(img + (size_t)(yy0 * W_DIM + xx1) * (C_DIM * 2));
        uint4 v2 = *(const uint4*)(img + (size_t)(yy1 * W_DIM + xx1) * (C_DIM * 2));
        uint4 v3 = *(const uint4*)(img + (size_t)(yy1 * W_DIM + xx0) * (C_DIM * 2));
        float w0 = wy0 * wx0;
        float w1 = wy0 * wx1;
        float w2 = wy1 * wx1;
        float w3 = wy1 * wx0;

        float acc[8] = {0.f, 0.f, 0.f, 0.f, 0.f, 0.f, 0.f, 0.f};
        auto accp = [&](float wt, const uint4& u) {
            acc[0] = fmaf(wt, __uint_as_float(u.x << 16),         acc[0]);
            acc[1] = fmaf(wt, __uint_as_float(u.x & 0xffff0000u), acc[1]);
            acc[2] = fmaf(wt, __uint_as_float(u.y << 16),         acc[2]);
            acc[3] = fmaf(wt, __uint_as_float(u.y & 0xffff0000u), acc[3]);
            acc[4] = fmaf(wt, __uint_as_float(u.z << 16),         acc[4]);
            acc[5] = fmaf(wt, __uint_as_float(u.z & 0xffff0000u), acc[5]);
            acc[6] = fmaf(wt, __uint_as_float(u.w << 16),         acc[6]);
            acc[7] = fmaf(wt, __uint_as_float(u.w & 0xffff0000u), acc[7]);
        };
        accp(w0, v0); accp(w1, v1); accp(w2, v2); accp(w3, v3);

        // reduce the 4 corners: xor8/xor16 stay inside each 32-lane half
        #pragma unroll
        for (int j = 0; j < 8; ++j) {
            acc[j] += __shfl_xor(acc[j], 8);
            acc[j] += __shfl_xor(acc[j], 16);
        }
        if (q == 0 && bb < NBINS) {
            #pragma unroll
            for (int j = 0; j < 8; ++j)
                s_out[(cg * 8 + j) * NBINS + bb] = acc[j] * 0.25f;
        }
    }
    __syncthreads();

    // coalesced nontemporal copy-out: 3136 floats = 784 float4, contiguous
    nfloat4* o4 = (nfloat4*)(out + (size_t)k * (C_DIM * NBINS) + (size_t)qa * 64 * NBINS);
    const nfloat4* s4 = (const nfloat4*)s_out;
    for (int i = t; i < (64 * NBINS) / 4; i += 256)
        __builtin_nontemporal_store(s4[i], o4 + i);
}

// ---------------- fallback (round-0 baseline) if ws too small ---------------
__global__ __launch_bounds__(256) void roi_align_naive(
    const float* __restrict__ input, const float* __restrict__ rois,
    float* __restrict__ out, int K)
{
    int idx = blockIdx.x * blockDim.x + threadIdx.x;
    int total = K * C_DIM * OUT_H * OUT_W;
    if (idx >= total) return;
    int ow = idx % OUT_W;
    int oh = (idx / OUT_W) % OUT_H;
    int c  = (idx / (OUT_W * OUT_H)) % C_DIM;
    int k  = idx / (OUT_W * OUT_H * C_DIM);
    const float* r = rois + (size_t)k * 5;
    int   b  = (int)r[0];
    float x1 = r[1] * SPATIAL_SCALE, y1 = r[2] * SPATIAL_SCALE;
    float x2 = r[3] * SPATIAL_SCALE, y2 = r[4] * SPATIAL_SCALE;
    float roi_w = fmaxf(x2 - x1, 1.0f), roi_h = fmaxf(y2 - y1, 1.0f);
    float bin_h = roi_h / OUT_H, bin_w = roi_w / OUT_W;
    const float* inp = input + ((size_t)b * C_DIM + c) * HW;
    float acc = 0.0f;
    #pragma unroll
    for (int sy = 0; sy < SR; ++sy) {
        float gy = y1 + bin_h * (((float)(oh * SR + sy) + 0.5f) / SR);
        bool vy = (gy >= -1.0f) && (gy <= (float)H_DIM);
        float y = fminf(fmaxf(gy, 0.0f), (float)(H_DIM - 1));
        int yl = (int)floorf(y); float ly = y - yl; int yh = min(yl + 1, H_DIM - 1);
        #pragma unroll
        for (int sx = 0; sx < SR; ++sx) {
            float gx = x1 + bin_w * (((float)(ow * SR + sx) + 0.5f) / SR);
            bool vx = (gx >= -1.0f) && (gx <= (float)W_DIM);
            float x = fminf(fmaxf(gx, 0.0f), (float)(W_DIM - 1));
            int xl = (int)floorf(x); float lx = x - xl; int xh = min(xl + 1, W_DIM - 1);
            float v = (1.0f - ly) * ((1.0f - lx) * inp[yl * W_DIM + xl] + lx * inp[yl * W_DIM + xh])
                    + ly * ((1.0f - lx) * inp[yh * W_DIM + xl] + lx * inp[yh * W_DIM + xh]);
            if (vy && vx) acc += v;
        }
    }
    out[idx] = acc * 0.25f;
}

extern "C" void kernel_launch(void* const* d_in, const int* in_sizes, int n_in,
                              void* d_out, int out_size, void* d_ws, size_t ws_size,
                              hipStream_t stream) {
    const float* input = (const float*)d_in[0];
    const float* rois  = (const float*)d_in[1];
    float* out = (float*)d_out;
    int K = in_sizes[1] / 5;

    if (ws_size >= NHWC_BF16_BYTES + (size_t)K * sizeof(int) && K <= MAX_BUCKET_K) {
        unsigned short* nhwc = (unsigned short*)d_ws;
        int* map = (int*)((char*)d_ws + NHWC_BF16_BYTES);
        dim3 tgrid(NT_SP + 1, C_DIM / 64, N_DIM);    // 80 x 4 x 8 (+1 = bucket)
        nchw_to_nhwc_bf16<<<tgrid, 256, 0, stream>>>(input, nhwc, rois, K, map);
        dim3 ggrid(K, 4);
        roi_gather_q<<<ggrid, 256, 0, stream>>>(nhwc, rois, map, out, K);
    } else if (ws_size >= NHWC_BF16_BYTES) {
        unsigned short* nhwc = (unsigned short*)d_ws;
        dim3 tgrid(NT_SP, C_DIM / 64, N_DIM);
        nchw_to_nhwc_bf16<<<tgrid, 256, 0, stream>>>(input, nhwc, rois, K, nullptr);
        dim3 ggrid(K, 4);
        roi_gather_q<<<ggrid, 256, 0, stream>>>(nhwc, rois, nullptr, out, K);
    } else {
        int total = K * C_DIM * OUT_H * OUT_W;
        roi_align_naive<<<(total + 255) / 256, 256, 0, stream>>>(input, rois, out, K);
    }
}

// Round 12
// 164.059 us; speedup vs baseline: 6.2423x; 1.0494x over previous
//
#include <hip/hip_runtime.h>

// ROI Align on MI355X.
// input: (N=8, C=256, H=100, W=100) fp32 NCHW; rois (K,5); out (K,256,7,7) fp32.
//
// Round 22: restore round-16 exactly (best measured: 163.8us). r21 proved the
// 128-sp transpose loses ~8us via occupancy (LDS 16.6->33KB, 8->4 blocks/CU);
// r20 proved unstaged gather stores cost 4.5x write amplification; r19 proved
// naive producer-consumer fusion collapses; r12 proved LDS-in-address-path
// costs latency. Four gather structures measured within noise -> gather is at
// its L2-latency floor. Remaining dur_us is ~46% harness fills + two kernels
// near their practical floors.

typedef float nfloat4 __attribute__((ext_vector_type(4)));
typedef unsigned short nushort8 __attribute__((ext_vector_type(8)));

constexpr int   OUT_H = 7;
constexpr int   OUT_W = 7;
constexpr int   NBINS = OUT_H * OUT_W;          // 49
constexpr int   NPAIRS = (NBINS + 1) / 2;       // 25 (last pair has 1 bin)
constexpr float SPATIAL_SCALE = 0.25f;
constexpr int   SR = 2;
constexpr int   N_DIM = 8;
constexpr int   C_DIM = 256;
constexpr int   H_DIM = 100;
constexpr int   W_DIM = 100;
constexpr int   HW    = H_DIM * W_DIM;          // 10000
constexpr size_t NHWC_BF16_BYTES = (size_t)N_DIM * HW * C_DIM * 2; // 40,960,000
constexpr int   MAX_BUCKET_K = 2048;

__device__ inline unsigned short f2bf_rne(float f) {
    unsigned u = __float_as_uint(f);
    u += 0x7fffu + ((u >> 16) & 1u);    // round-to-nearest-even
    return (unsigned short)(u >> 16);
}

// ---------------- transpose+cast + bucket (fused) ---------------------------
// blocks x<157: NCHW fp32 -> NHWC bf16, 64ch x 64sp tile, LDS stride 65.
// block (157,0,0): bucket -> map[k] = ROI index with batch ~= k%8.
constexpr int TP = 65;

union TransposeSh {
    float tile[64 * TP];                                   // 16640 B
    struct {
        int cnt[8]; int ovfCnt; int holeCnt;
        int ovf[MAX_BUCKET_K]; int holes[MAX_BUCKET_K];    // 16424 B
    } bk;
};

__global__ __launch_bounds__(256) void nchw_to_nhwc_bf16(
    const float* __restrict__ in, unsigned short* __restrict__ out,
    const float* __restrict__ rois, int K, int* __restrict__ map)
{
    __shared__ TransposeSh sh;
    int bx = blockIdx.x;
    int t  = threadIdx.x;

    if (bx == (HW + 63) / 64) {
        // ---- bucket branch: one block does the batch->position map ----
        if (blockIdx.y != 0 || blockIdx.z != 0 || map == nullptr) return;
        if (t < 8) sh.bk.cnt[t] = 0;
        if (t == 0) { sh.bk.ovfCnt = 0; sh.bk.holeCnt = 0; }
        for (int i = t; i < K; i += 256) map[i] = -1;
        __syncthreads();
        int per = K / 8;
        for (int i = t; i < K; i += 256) {
            int b = ((int)rois[(size_t)i * 5]) & 7;
            int r = atomicAdd(&sh.bk.cnt[b], 1);
            if (r < per) map[b + 8 * r] = i;
            else sh.bk.ovf[atomicAdd(&sh.bk.ovfCnt, 1)] = i;
        }
        __syncthreads();
        for (int i = t; i < K; i += 256)
            if (map[i] == -1) sh.bk.holes[atomicAdd(&sh.bk.holeCnt, 1)] = i;
        __syncthreads();
        for (int i = t; i < sh.bk.ovfCnt; i += 256)
            map[sh.bk.holes[i]] = sh.bk.ovf[i];
        return;
    }

    // ---- transpose branch ----
    int s0 = bx * 64;
    int c0 = blockIdx.y * 64;
    int n  = blockIdx.z;

    int sl4 = (t & 15) * 4;
    int cq  = t >> 4;                  // 0..15

    #pragma unroll
    for (int r = 0; r < 4; ++r) {
        int cl = r * 16 + cq;
        int s  = s0 + sl4;
        const float* src = in + ((size_t)(n * C_DIM + c0 + cl) * HW + s);
        if (s + 3 < HW) {
            nfloat4 v = __builtin_nontemporal_load((const nfloat4*)src);
            sh.tile[cl * TP + sl4 + 0] = v.x;
            sh.tile[cl * TP + sl4 + 1] = v.y;
            sh.tile[cl * TP + sl4 + 2] = v.z;
            sh.tile[cl * TP + sl4 + 3] = v.w;
        } else {
            #pragma unroll
            for (int i = 0; i < 4; ++i)
                sh.tile[cl * TP + sl4 + i] = (s + i < HW) ? src[i] : 0.0f;
        }
    }
    __syncthreads();

    // write-out: 2 passes, 8 channels/thread, one 16B ushort8 store each.
    // LDS read bank = ((c8+j)*65 + sp) % 32 = (8*(t&7)+j+(t>>3)) % 32 -> 2-way.
    #pragma unroll
    for (int p = 0; p < 2; ++p) {
        int sp = p * 32 + (t >> 3);
        int s  = s0 + sp;
        int c8 = (t & 7) * 8;
        if (s < HW) {
            nushort8 h;
            #pragma unroll
            for (int j = 0; j < 8; ++j)
                h[j] = f2bf_rne(sh.tile[(c8 + j) * TP + sp]);
            *(nushort8*)(out + ((size_t)n * HW + s) * C_DIM + c0 + c8) = h;
        }
    }
}

// ---------------- gather: quarter-channel blocks, 2-bin pairs per wave ------
// block = (ROI via map, 64-ch quarter); wave iterates bin-PAIRS (stride 4).
// lane = hi*32 + q*8 + cg:  hi = which bin of the pair, q = corner, cg = 8-ch
// group. Per iteration: 8 broadcast Geom reads + 8 independent uint4 loads
// (4 samples x this lane's corner, both bins) + 32 fma; corner reduce =
// shfl_xor(8),shfl_xor(16) within each 32-lane half (2 bins per 16 shfl).
// s_out staging kept: assembles line-complete contiguous stores (r20 showed
// direct scattered 4B stores cost 4.5x write amplification).
struct alignas(16) Geom { int lo; int hi; float wv; float mwv; };

__global__ __launch_bounds__(256, 6) void roi_gather_q(
    const unsigned short* __restrict__ nhwc,
    const float* __restrict__ rois,
    const int* __restrict__ map,
    float* __restrict__ out, int K)
{
    __shared__ float s_out[64 * NBINS];    // 12544 B
    __shared__ Geom xg[OUT_W * SR];        // 14
    __shared__ Geom yg[OUT_H * SR];        // 14

    int k  = map ? map[blockIdx.x] : (int)blockIdx.x;
    int qa = blockIdx.y;                   // channel quarter 0..3
    const float* r = rois + (size_t)k * 5;
    int   b  = (int)r[0];
    float x1 = r[1] * SPATIAL_SCALE;
    float y1 = r[2] * SPATIAL_SCALE;
    float x2 = r[3] * SPATIAL_SCALE;
    float y2 = r[4] * SPATIAL_SCALE;
    float roi_w = fmaxf(x2 - x1, 1.0f);
    float roi_h = fmaxf(y2 - y1, 1.0f);
    float bin_h = roi_h / (float)OUT_H;
    float bin_w = roi_w / (float)OUT_W;

    int t = threadIdx.x;
    // fill geometry: threads 0..13 -> x, 64..77 -> y (separate waves)
    if (t < OUT_W * SR) {
        float g = x1 + bin_w * (((float)t + 0.5f) * 0.5f);
        float v = (g >= -1.0f && g <= (float)W_DIM) ? 1.0f : 0.0f;
        float x = fminf(fmaxf(g, 0.0f), (float)(W_DIM - 1));
        int   lo = (int)floorf(x);
        float l  = x - (float)lo;
        xg[t].lo = lo; xg[t].hi = min(lo + 1, W_DIM - 1);
        xg[t].wv = l * v; xg[t].mwv = (1.0f - l) * v;
    } else if (t >= 64 && t < 64 + OUT_H * SR) {
        int i = t - 64;
        float g = y1 + bin_h * (((float)i + 0.5f) * 0.5f);
        float v = (g >= -1.0f && g <= (float)H_DIM) ? 1.0f : 0.0f;
        float y = fminf(fmaxf(g, 0.0f), (float)(H_DIM - 1));
        int   lo = (int)floorf(y);
        float l  = y - (float)lo;
        yg[i].lo = lo; yg[i].hi = min(lo + 1, H_DIM - 1);
        yg[i].wv = l * v; yg[i].mwv = (1.0f - l) * v;
    }
    __syncthreads();

    int wave = t >> 6;
    int lane = t & 63;
    int hi   = lane >> 5;                  // which bin of the pair
    int q    = (lane >> 3) & 3;            // corner: 0=ll 1=lh 2=hl 3=hh
    int cg   = lane & 7;                   // 8-channel group within quarter
    int qy   = q >> 1;
    int qx   = q & 1;

    const char* img = (const char*)nhwc
        + (size_t)b * HW * (C_DIM * 2) + qa * 128 + cg * 16;

    for (int p = wave; p < NPAIRS; p += 4) {
        int bb  = 2 * p + hi;                      // 0..49 (49 = pad)
        int bbc = bb < NBINS ? bb : NBINS - 1;
        int oh  = bbc / OUT_W;
        int ow  = bbc - oh * OUT_W;

        Geom gy0 = yg[oh * SR + 0];
        Geom gy1 = yg[oh * SR + 1];
        Geom gx0 = xg[ow * SR + 0];
        Geom gx1 = xg[ow * SR + 1];
        int   yy0 = qy ? gy0.hi : gy0.lo;  float wy0 = qy ? gy0.wv : gy0.mwv;
        int   yy1 = qy ? gy1.hi : gy1.lo;  float wy1 = qy ? gy1.wv : gy1.mwv;
        int   xx0 = qx ? gx0.hi : gx0.lo;  float wx0 = qx ? gx0.wv : gx0.mwv;
        int   xx1 = qx ? gx1.hi : gx1.lo;  float wx1 = qx ? gx1.wv : gx1.mwv;

        // 4 samples (sy,sx) for this lane's corner, this lane's bin
        uint4 v0 = *(const uint4*)(img + (size_t)(yy0 * W_DIM + xx0) * (C_DIM * 2));
        uint4 v1 = *(const uint4*)(img + (size_t)(yy0 * W_DIM + xx1) * (C_DIM * 2));
        uint4 v2 = *(const uint4*)(img + (size_t)(yy1 * W_DIM + xx1) * (C_DIM * 2));
        uint4 v3 = *(const uint4*)(img + (size_t)(yy1 * W_DIM + xx0) * (C_DIM * 2));
        float w0 = wy0 * wx0;
        float w1 = wy0 * wx1;
        float w2 = wy1 * wx1;
        float w3 = wy1 * wx0;

        float acc[8] = {0.f, 0.f, 0.f, 0.f, 0.f, 0.f, 0.f, 0.f};
        auto accp = [&](float wt, const uint4& u) {
            acc[0] = fmaf(wt, __uint_as_float(u.x << 16),         acc[0]);
            acc[1] = fmaf(wt, __uint_as_float(u.x & 0xffff0000u), acc[1]);
            acc[2] = fmaf(wt, __uint_as_float(u.y << 16),         acc[2]);
            acc[3] = fmaf(wt, __uint_as_float(u.y & 0xffff0000u), acc[3]);
            acc[4] = fmaf(wt, __uint_as_float(u.z << 16),         acc[4]);
            acc[5] = fmaf(wt, __uint_as_float(u.z & 0xffff0000u), acc[5]);
            acc[6] = fmaf(wt, __uint_as_float(u.w << 16),         acc[6]);
            acc[7] = fmaf(wt, __uint_as_float(u.w & 0xffff0000u), acc[7]);
        };
        accp(w0, v0); accp(w1, v1); accp(w2, v2); accp(w3, v3);

        // reduce the 4 corners: xor8/xor16 stay inside each 32-lane half
        #pragma unroll
        for (int j = 0; j < 8; ++j) {
            acc[j] += __shfl_xor(acc[j], 8);
            acc[j] += __shfl_xor(acc[j], 16);
        }
        if (q == 0 && bb < NBINS) {
            #pragma unroll
            for (int j = 0; j < 8; ++j)
                s_out[(cg * 8 + j) * NBINS + bb] = acc[j] * 0.25f;
        }
    }
    __syncthreads();

    // coalesced nontemporal copy-out: 3136 floats = 784 float4, contiguous
    nfloat4* o4 = (nfloat4*)(out + (size_t)k * (C_DIM * NBINS) + (size_t)qa * 64 * NBINS);
    const nfloat4* s4 = (const nfloat4*)s_out;
    for (int i = t; i < (64 * NBINS) / 4; i += 256)
        __builtin_nontemporal_store(s4[i], o4 + i);
}

// ---------------- fallback (round-0 baseline) if ws too small ---------------
__global__ __launch_bounds__(256) void roi_align_naive(
    const float* __restrict__ input, const float* __restrict__ rois,
    float* __restrict__ out, int K)
{
    int idx = blockIdx.x * blockDim.x + threadIdx.x;
    int total = K * C_DIM * OUT_H * OUT_W;
    if (idx >= total) return;
    int ow = idx % OUT_W;
    int oh = (idx / OUT_W) % OUT_H;
    int c  = (idx / (OUT_W * OUT_H)) % C_DIM;
    int k  = idx / (OUT_W * OUT_H * C_DIM);
    const float* r = rois + (size_t)k * 5;
    int   b  = (int)r[0];
    float x1 = r[1] * SPATIAL_SCALE, y1 = r[2] * SPATIAL_SCALE;
    float x2 = r[3] * SPATIAL_SCALE, y2 = r[4] * SPATIAL_SCALE;
    float roi_w = fmaxf(x2 - x1, 1.0f), roi_h = fmaxf(y2 - y1, 1.0f);
    float bin_h = roi_h / OUT_H, bin_w = roi_w / OUT_W;
    const float* inp = input + ((size_t)b * C_DIM + c) * HW;
    float acc = 0.0f;
    #pragma unroll
    for (int sy = 0; sy < SR; ++sy) {
        float gy = y1 + bin_h * (((float)(oh * SR + sy) + 0.5f) / SR);
        bool vy = (gy >= -1.0f) && (gy <= (float)H_DIM);
        float y = fminf(fmaxf(gy, 0.0f), (float)(H_DIM - 1));
        int yl = (int)floorf(y); float ly = y - yl; int yh = min(yl + 1, H_DIM - 1);
        #pragma unroll
        for (int sx = 0; sx < SR; ++sx) {
            float gx = x1 + bin_w * (((float)(ow * SR + sx) + 0.5f) / SR);
            bool vx = (gx >= -1.0f) && (gx <= (float)W_DIM);
            float x = fminf(fmaxf(gx, 0.0f), (float)(W_DIM - 1));
            int xl = (int)floorf(x); float lx = x - xl; int xh = min(xl + 1, W_DIM - 1);
            float v = (1.0f - ly) * ((1.0f - lx) * inp[yl * W_DIM + xl] + lx * inp[yl * W_DIM + xh])
                    + ly * ((1.0f - lx) * inp[yh * W_DIM + xl] + lx * inp[yh * W_DIM + xh]);
            if (vy && vx) acc += v;
        }
    }
    out[idx] = acc * 0.25f;
}

extern "C" void kernel_launch(void* const* d_in, const int* in_sizes, int n_in,
                              void* d_out, int out_size, void* d_ws, size_t ws_size,
                              hipStream_t stream) {
    const float* input = (const float*)d_in[0];
    const float* rois  = (const float*)d_in[1];
    float* out = (float*)d_out;
    int K = in_sizes[1] / 5;
    int ntiles = (HW + 63) / 64;    // 157

    if (ws_size >= NHWC_BF16_BYTES + (size_t)K * sizeof(int) && K <= MAX_BUCKET_K) {
        unsigned short* nhwc = (unsigned short*)d_ws;
        int* map = (int*)((char*)d_ws + NHWC_BF16_BYTES);
        dim3 tgrid(ntiles + 1, C_DIM / 64, N_DIM);   // 158 x 4 x 8 (+1 = bucket block)
        nchw_to_nhwc_bf16<<<tgrid, 256, 0, stream>>>(input, nhwc, rois, K, map);
        dim3 ggrid(K, 4);
        roi_gather_q<<<ggrid, 256, 0, stream>>>(nhwc, rois, map, out, K);
    } else if (ws_size >= NHWC_BF16_BYTES) {
        unsigned short* nhwc = (unsigned short*)d_ws;
        dim3 tgrid(ntiles, C_DIM / 64, N_DIM);
        nchw_to_nhwc_bf16<<<tgrid, 256, 0, stream>>>(input, nhwc, rois, K, nullptr);
        dim3 ggrid(K, 4);
        roi_gather_q<<<ggrid, 256, 0, stream>>>(nhwc, rois, nullptr, out, K);
    } else {
        int total = K * C_DIM * OUT_H * OUT_W;
        roi_align_naive<<<(total + 255) / 256, 256, 0, stream>>>(input, rois, out, K);
    }
}